// Round 5
// baseline (230.258 us; speedup 1.0000x reference)
//
#include <hip/hip_runtime.h>
#include <cstdint>
#include <cstddef>

// ---------------------------------------------------------------------------
// SparseMHADecoder: B=2, LQ=4096, LKV=2048, D=1024, H=16, d=64, span=16, stride=2
// R11: cut staging instruction traffic + drains (T4 counted-vmcnt everywhere).
//  - gemm_qkv: B staged via global_load_lds (pre-swizzled global src, linear
//    LDS dest, m173/R6-verified). No B reg loads, no B ds_writes. Barrier wait
//    becomes vmcnt(8)+lgkmcnt(0) — the 8 A-loads for t+2 stay in flight.
//    A stays f32 reg-staged (cvt folded). Main loop unroll 2 (was 16; I$).
//  - gemm_out: BOTH operands via global_load_lds, TRIPLE-buffered LDS
//    (3 x 48KB), distance-2 staging, counted vmcnt(6) per K-tile, no ds_writes,
//    no staging regs at all.
// R10 carried: coalesced staging geometry (FETCH 42MB = near-ideal), XCD
//    A-panel grouping, distance-2 pipeline, one barrier per K-tile, setprio.
// R6/R5 carried: XOR chunk swizzle (0 bank conflicts all rounds), f16 numerics.
// ---------------------------------------------------------------------------

typedef _Float16 f16;
typedef _Float16 f16x8 __attribute__((ext_vector_type(8)));
typedef float v4f __attribute__((ext_vector_type(4)));

#define B_  2
#define LQ_ 4096
#define LKV_ 2048
#define DMODEL 1024
#define NH 16
#define HD 64
#define SPAN 16
#define STRIDE 2

#define NQ_ELEMS  ((size_t)B_ * LQ_ * DMODEL)   // 8388608
#define NKV_ELEMS ((size_t)B_ * LKV_ * DMODEL)  // 4194304

__device__ __forceinline__ void async_copy16(const f16* g, f16* l) {
    __builtin_amdgcn_global_load_lds((const __attribute__((address_space(1))) void*)g,
                                     (__attribute__((address_space(3))) void*)l, 16, 0, 0);
}

// ------------- prep: 4 weight transposes, Wt[n][k] = (f16)W[k][n] ------------
__global__ __launch_bounds__(256)
void transpose_all(const float* __restrict__ W0, const float* __restrict__ W1,
                   const float* __restrict__ W2, const float* __restrict__ W3,
                   f16* __restrict__ T0, f16* __restrict__ T1,
                   f16* __restrict__ T2, f16* __restrict__ T3) {
    const int t = threadIdx.x;
    const int bid = blockIdx.x;             // 1024 = 16x16 tiles x 4 weights
    const int z = bid >> 8, rem = bid & 255;
    const int bx = rem & 15, byy = rem >> 4;
    const float* W;
    f16* Wt;
    switch (z) {
        case 0: W = W0; Wt = T0; break;
        case 1: W = W1; Wt = T1; break;
        case 2: W = W2; Wt = T2; break;
        default: W = W3; Wt = T3; break;
    }
    __shared__ float tile[64][65];
    const int r0 = byy * 64, c0 = bx * 64;
    const int tx = t & 63, ty = t >> 6;     // (64,4)
    for (int i = ty; i < 64; i += 4)
        tile[i][tx] = W[(long)(r0 + i) * DMODEL + c0 + tx];
    __syncthreads();
    for (int i = ty; i < 64; i += 4)
        Wt[(long)(c0 + i) * DMODEL + r0 + tx] = (f16)tile[tx][i];
}

// ---------------------------------------------------------------------------
// gemm_qkv body: C[m][n] = sum_k A_f32[m][k] * Bt_f16[n][k]
// BM=BN=256, BK=64, 512 thr = 8 waves (2M x 4N), wave tile 128x64, acc[8][4].
// A: f32 global -> reg -> cvt -> ds_write (swizzled LDS side), double-buffered.
// B: global_load_lds, swizzle on the GLOBAL side, linear LDS, double-buffered.
// Per K-tile barrier: s_waitcnt vmcnt(8) lgkmcnt(0)  (8 = A-loads for t+2
// still in flight; retires the 4 older B gloads for t+1). Never vmcnt(0)
// mid-loop (T4).
// ---------------------------------------------------------------------------
__device__ __forceinline__ void gemm_qkv_body(const float* __restrict__ A,
                                              const f16* __restrict__ Bt,
                                              f16* __restrict__ C,
                                              int rowTile, int colTile) {
    constexpr int BM = 256, BN = 256, BK = 64, K = DMODEL, N = DMODEL, NT = K / BK;
    constexpr int LA = BM * BK;             // 16384 f16
    constexpr int LB = BN * BK;             // 16384 f16
    __shared__ f16 As[2 * LA];              // 64 KB
    __shared__ f16 Bs[2 * LB];              // 64 KB

    const int t = threadIdx.x;              // 512
    const int lane = t & 63, w = t >> 6;
    const int wm = w >> 2, wn = w & 3;
    const int qrow = lane & 15, quad = lane >> 4;
    const long rowBase = (long)rowTile * BM;
    const long colBase = (long)colTile * BN;

    // staging geometry: chunk l of rows g+64i (coalesced per 8-lane group)
    const int l = t & 7, g = t >> 3;
    const int lsw = (l ^ (g & 7)) * 8;      // thread-constant swizzled chunk

    // A: LINEAR global source (swizzle applied on the ds_write side)
    const float* gAf = A + (rowBase + g) * (long)K + l * 8;
    // B: SWIZZLED global source, LINEAR LDS dest (= t*16 bytes per instr)
    const f16* gBsw = Bt + (colBase + g) * (long)K + lsw;

    int offA[4];
#pragma unroll
    for (int i = 0; i < 4; ++i) offA[i] = (g + 64 * i) * BK + lsw;

    int offAf[8], offBf[4];
#pragma unroll
    for (int m = 0; m < 8; ++m) offAf[m] = (wm * 128 + m * 16 + qrow) * BK;
#pragma unroll
    for (int n = 0; n < 4; ++n) offBf[n] = (wn * 64 + n * 16 + qrow) * BK;

    float4 ra[8];                           // single staging reg set (32 VGPR)
    v4f acc[8][4] = {};

    auto GLOADB = [&](int tt) {
        f16* lB = &Bs[(tt & 1) * LB + t * 8];
#pragma unroll
        for (int i = 0; i < 4; ++i)
            async_copy16(gBsw + (long)i * 64 * K + tt * BK, lB + i * 4096);
    };

    auto LOADA = [&](int tt) {
#pragma unroll
        for (int i = 0; i < 4; ++i) {
            ra[2 * i]     = *(const float4*)(gAf + (long)i * 64 * K + tt * BK);
            ra[2 * i + 1] = *(const float4*)(gAf + (long)i * 64 * K + tt * BK + 4);
        }
    };

    auto WRITEA = [&](int tt) {
        f16* lp = &As[(tt & 1) * LA];
#pragma unroll
        for (int i = 0; i < 4; ++i) {
            float4 lo = ra[2 * i], hi = ra[2 * i + 1];
            f16x8 o = {(f16)lo.x, (f16)lo.y, (f16)lo.z, (f16)lo.w,
                       (f16)hi.x, (f16)hi.y, (f16)hi.z, (f16)hi.w};
            *(f16x8*)(lp + offA[i]) = o;
        }
    };

    auto COMPUTE = [&](int tt) {
        const f16* lA = &As[(tt & 1) * LA];
        const f16* lB = &Bs[(tt & 1) * LB];
#pragma unroll
        for (int s = 0; s < 2; ++s) {
            const int xk = ((s * 4 + quad) ^ (qrow & 7)) * 8;
            f16x8 bfr[4];
#pragma unroll
            for (int n = 0; n < 4; ++n) bfr[n] = *(const f16x8*)(lB + offBf[n] + xk);
            __builtin_amdgcn_s_setprio(1);
#pragma unroll
            for (int m = 0; m < 8; ++m) {
                f16x8 afr = *(const f16x8*)(lA + offAf[m] + xk);
#pragma unroll
                for (int n = 0; n < 4; ++n)
                    acc[m][n] = __builtin_amdgcn_mfma_f32_16x16x32_f16(
                        afr, bfr[n], acc[m][n], 0, 0, 0);
            }
            __builtin_amdgcn_s_setprio(0);
        }
    };

    // ---- prologue: B(0) DMA, A(0) regs -> LDS, A(1) in flight ----
    GLOADB(0);
    asm volatile("" ::: "memory");          // keep B(0) oldest in vmcnt order
    LOADA(0);
    WRITEA(0);   // compiler's counted vmcnt for A(0) also retires older B(0)
    LOADA(1);
    asm volatile("s_waitcnt lgkmcnt(0)" ::: "memory");
    __builtin_amdgcn_s_barrier();
    asm volatile("" ::: "memory");

    // ---- main loop: one barrier per K-tile, counted vmcnt ----
#pragma unroll 2
    for (int tt = 0; tt < NT; ++tt) {
        if (tt + 1 < NT) {
            GLOADB(tt + 1);                 // 4 vmem, oldest of this iter
            asm volatile("" ::: "memory");
            WRITEA(tt + 1);                 // regs loaded at iter tt-1
        }
        if (tt + 2 < NT) LOADA(tt + 2);     // 8 vmem, newer than B(t+1)
        COMPUTE(tt);
        if (tt + 1 < NT) {
            if (tt + 2 < NT)
                asm volatile("s_waitcnt vmcnt(8) lgkmcnt(0)" ::: "memory");
            else
                asm volatile("s_waitcnt vmcnt(0) lgkmcnt(0)" ::: "memory");
            __builtin_amdgcn_s_barrier();
            asm volatile("" ::: "memory");
        }
    }

    // ---- epilogue: C/D layout (m89-verified): row = quad*4 + r, col = qrow --
#pragma unroll
    for (int m = 0; m < 8; ++m)
#pragma unroll
        for (int n = 0; n < 4; ++n) {
            const long col = colBase + wn * 64 + n * 16 + qrow;
#pragma unroll
            for (int r = 0; r < 4; ++r) {
                const long row = rowBase + wm * 128 + m * 16 + quad * 4 + r;
                C[row * (long)N + col] = (f16)acc[m][n][r];
            }
        }
}

__global__ __launch_bounds__(512)
void gemm_qkv(const float* __restrict__ q, const float* __restrict__ k,
              const float* __restrict__ v, const f16* __restrict__ WqT,
              const f16* __restrict__ WkT, const f16* __restrict__ WvT,
              f16* __restrict__ Qh, f16* __restrict__ Kh, f16* __restrict__ Vh) {
    const int id = (blockIdx.x & 7) * 32 + (blockIdx.x >> 3);  // bijective, 256
    const float* A; const f16* Bt; f16* C; int rt, ct;
    if (id < 128)      { A = q; Bt = WqT; C = Qh; rt = id >> 2; ct = id & 3; }
    else if (id < 192) { const int g = id - 128; A = k; Bt = WkT; C = Kh; rt = g >> 2; ct = g & 3; }
    else               { const int g = id - 192; A = v; Bt = WvT; C = Vh; rt = g >> 2; ct = g & 3; }
    gemm_qkv_body(A, Bt, C, rt, ct);
}

// ---------------------------------------------------------------------------
// gemm_out: C_f32[m][n] = sum_k A_f16[m][k] * Bt_f16[n][k]
// BM=256, BN=128, BK=64, 512 thr = 8 waves (4M x 2N), wave 64x64, acc[4][4].
// BOTH operands via global_load_lds (swizzled global src, linear LDS),
// TRIPLE-buffered (3 x 48KB = 144KB): stage tile t+2 while computing t.
// Per K-tile barrier: s_waitcnt vmcnt(6) (the 6 gloads for t+2 in flight,
// retiring the 6 older ones for t+1). No ds_writes, no staging regs.
// ---------------------------------------------------------------------------
__global__ __launch_bounds__(512)
void gemm_out(const f16* __restrict__ Ap, const f16* __restrict__ Bt,
              float* __restrict__ C) {
    constexpr int BM = 256, BN = 128, BK = 64, K = DMODEL, N = DMODEL, NT = K / BK;
    constexpr int LAE = BM * BK;            // 16384 f16 (A region elems)
    constexpr int LT = (BM + BN) * BK;      // 24576 f16 per tile buffer
    __shared__ f16 lds[3 * LT];             // 144 KB

    const int id = (blockIdx.x & 7) * 32 + (blockIdx.x >> 3);
    const int rt = id >> 3, ct = id & 7;    // A-panel shared per XCD

    const int t = threadIdx.x;
    const int lane = t & 63, w = t >> 6;
    const int wm = w >> 1, wn = w & 1;
    const int qrow = lane & 15, quad = lane >> 4;
    const long rowBase = (long)rt * BM;
    const long colBase = (long)ct * BN;

    const int l = t & 7, g = t >> 3;
    const int lsw = (l ^ (g & 7)) * 8;

    const f16* gAsw = Ap + (rowBase + g) * (long)K + lsw;
    const f16* gBsw = Bt + (colBase + g) * (long)K + lsw;

    int offAf[4], offBf[4];
#pragma unroll
    for (int m = 0; m < 4; ++m) offAf[m] = (wm * 64 + m * 16 + qrow) * BK;
#pragma unroll
    for (int n = 0; n < 4; ++n) offBf[n] = LAE + (wn * 64 + n * 16 + qrow) * BK;

    v4f acc[4][4] = {};

    f16* b0 = lds;
    f16* b1 = lds + LT;
    f16* b2 = lds + 2 * LT;

    auto GLOAD = [&](int tt, f16* buf) {
        f16* lA = buf + t * 8;
        f16* lB = buf + LAE + t * 8;
#pragma unroll
        for (int i = 0; i < 4; ++i)
            async_copy16(gAsw + (long)i * 64 * K + tt * BK, lA + i * 4096);
#pragma unroll
        for (int i = 0; i < 2; ++i)
            async_copy16(gBsw + (long)i * 64 * K + tt * BK, lB + i * 4096);
    };

    auto COMPUTE = [&](const f16* buf) {
#pragma unroll
        for (int s = 0; s < 2; ++s) {
            const int xk = ((s * 4 + quad) ^ (qrow & 7)) * 8;
            f16x8 bfr[4];
#pragma unroll
            for (int n = 0; n < 4; ++n) bfr[n] = *(const f16x8*)(buf + offBf[n] + xk);
            __builtin_amdgcn_s_setprio(1);
#pragma unroll
            for (int m = 0; m < 4; ++m) {
                f16x8 afr = *(const f16x8*)(buf + offAf[m] + xk);
#pragma unroll
                for (int n = 0; n < 4; ++n)
                    acc[m][n] = __builtin_amdgcn_mfma_f32_16x16x32_f16(
                        afr, bfr[n], acc[m][n], 0, 0, 0);
            }
            __builtin_amdgcn_s_setprio(0);
        }
    };

    // ---- prologue: tiles 0 and 1 in flight; wait only tile 0 ----
    GLOAD(0, b0);
    GLOAD(1, b1);
    asm volatile("s_waitcnt vmcnt(6)" ::: "memory");   // tile0's 6 retired
    __builtin_amdgcn_s_barrier();
    asm volatile("" ::: "memory");

    for (int tt = 0; tt < NT; ++tt) {
        if (tt + 2 < NT) GLOAD(tt + 2, b2);            // 6 vmem, in flight
        COMPUTE(b0);
        if (tt + 1 < NT) {
            if (tt + 2 < NT)
                asm volatile("s_waitcnt vmcnt(6)" ::: "memory");  // t+1 done
            else
                asm volatile("s_waitcnt vmcnt(0)" ::: "memory");
            __builtin_amdgcn_s_barrier();
            asm volatile("" ::: "memory");
        }
        f16* tmp = b0; b0 = b1; b1 = b2; b2 = tmp;     // rotate
    }

    // ---- epilogue (f32 out) ----
#pragma unroll
    for (int m = 0; m < 4; ++m)
#pragma unroll
        for (int n = 0; n < 4; ++n) {
            const long col = colBase + wn * 64 + n * 16 + qrow;
#pragma unroll
            for (int r = 0; r < 4; ++r) {
                const long row = rowBase + wm * 64 + m * 16 + quad * 4 + r;
                C[row * (long)N + col] = acc[m][n][r];
            }
        }
}

// -------- per-column scores + softmax over the 16 valid query rows ----------
__global__ __launch_bounds__(256)
void attn_scores(const f16* __restrict__ Q, const f16* __restrict__ Km,
                 float* __restrict__ attnw) {
    const int c0 = blockIdx.x * 4, b = blockIdx.y;
    const int t = threadIdx.x;
    __shared__ f16 Qs[24 * 1032];   // rows 0..21 used; 49.5 KB
    __shared__ f16 Ks[4 * 1032];    // 8.25 KB

#pragma unroll
    for (int it = 0; it < 12; ++it) {
        const int ch = t + 256 * it;        // 24 rows x 128 chunks
        const int row = ch >> 7, off = (ch & 127) * 8;
        int qq = 2 * c0 + row;
        if (qq > LQ_ - 1) qq = LQ_ - 1;     // clamp staging; masked in score
        f16x8 x = *(const f16x8*)(Q + (size_t)(b * LQ_ + qq) * DMODEL + off);
        const int h = off >> 6, bb = (off >> 3) & 7;
        *(f16x8*)(&Qs[row * 1032 + h * 64 + ((bb + h) & 7) * 8]) = x;
    }
#pragma unroll
    for (int it = 0; it < 2; ++it) {
        const int ch = t + 256 * it;        // 4 rows x 128 chunks
        const int row = ch >> 7, off = (ch & 127) * 8;
        f16x8 x = *(const f16x8*)(Km + (size_t)(b * LKV_ + c0 + row) * DMODEL + off);
        const int h = off >> 6, bb = (off >> 3) & 7;
        *(f16x8*)(&Ks[row * 1032 + h * 64 + ((bb + h) & 7) * 8]) = x;
    }
    __syncthreads();

    const int h = t >> 4, j = t & 15;
#pragma unroll
    for (int ci = 0; ci < 4; ++ci) {
        const int c = c0 + ci;
        const int q = STRIDE * c + j;
        const int row = 2 * ci + j;
        float a = 0.f;
#pragma unroll
        for (int bb = 0; bb < 8; ++bb) {
            const int off = h * 64 + ((bb + h) & 7) * 8;
            f16x8 qv = *(const f16x8*)(&Qs[row * 1032 + off]);
            f16x8 kv = *(const f16x8*)(&Ks[ci * 1032 + off]);  // wave-broadcast
#pragma unroll
            for (int u = 0; u < 8; ++u) a += (float)qv[u] * (float)kv[u];
        }
        float s = (q < LQ_) ? a : -1e30f;
        float m = s;
#pragma unroll
        for (int o = 1; o < 16; o <<= 1) m = fmaxf(m, __shfl_xor(m, o, 64));
        float p = (q < LQ_) ? __expf(s - m) : 0.f;
        float sum = p;
#pragma unroll
        for (int o = 1; o < 16; o <<= 1) sum += __shfl_xor(sum, o, 64);
        attnw[(size_t)((b * LKV_ + c) * NH + h) * SPAN + j] = p / sum;
    }
}

// ---- ctx[b,q,h,:] = sum_i attn[b, q/2-i, h, (q&1)+2i] * V[b, q/2-i, h, :] ----
__global__ __launch_bounds__(256)
void ctx_gather(const float* __restrict__ attnw, const f16* __restrict__ V,
                f16* __restrict__ ctx) {
    const int q0 = blockIdx.x * 16, b = blockIdx.y;
    const int t = threadIdx.x;
    const int kbase = (q0 >> 1) - 7;
    __shared__ f16 Vs[16 * 1024];     // 32 KB
    __shared__ float A_lds[16 * 256]; // 16 KB

#pragma unroll
    for (int it = 0; it < 8; ++it) {
        const int ch = t + 256 * it;       // 16 rows x 128 chunks
        const int row = ch >> 7, off = (ch & 127) * 8;
        int k = kbase + row;
        k = (k < 0) ? 0 : ((k > LKV_ - 1) ? LKV_ - 1 : k);
        *(f16x8*)(&Vs[row * 1024 + off]) =
            *(const f16x8*)(V + (size_t)(b * LKV_ + k) * DMODEL + off);
    }
#pragma unroll
    for (int it = 0; it < 4; ++it) {
        const int ch = t + 256 * it;       // 16 rows x 64 chunks of 4 f32
        const int row = ch >> 6, off = (ch & 63) * 4;
        int k = kbase + row;
        k = (k < 0) ? 0 : ((k > LKV_ - 1) ? LKV_ - 1 : k);
        *(float4*)(&A_lds[row * 256 + off]) =
            *(const float4*)(attnw + (size_t)(b * LKV_ + k) * 256 + off);
    }
    __syncthreads();

    const int d = t & 63;
    const int hg = t >> 6;
#pragma unroll
    for (int ql = 0; ql < 16; ++ql) {
        const int q = q0 + ql;
        const int j0 = q & 1;
        float acc[4] = {0.f, 0.f, 0.f, 0.f};
#pragma unroll
        for (int i = 0; i < SPAN / STRIDE; ++i) {
            const int kq = (q >> 1) - i;
            if (kq < 0) break;
            const int rr = kq - kbase;
#pragma unroll
            for (int hh = 0; hh < 4; ++hh) {
                const int h = hg * 4 + hh;
                acc[hh] += A_lds[rr * 256 + h * 16 + j0 + 2 * i] *
                           (float)Vs[rr * 1024 + h * 64 + d];
            }
        }
        f16* crow = ctx + (size_t)(b * LQ_ + q) * DMODEL;
#pragma unroll
        for (int hh = 0; hh < 4; ++hh) {
            const int h = hg * 4 + hh;
            crow[h * HD + d] = (f16)acc[hh];
        }
    }
}

// ---------------------------------------------------------------------------
extern "C" void kernel_launch(void* const* d_in, const int* in_sizes, int n_in,
                              void* d_out, int out_size, void* d_ws, size_t ws_size,
                              hipStream_t stream) {
    const float* q  = (const float*)d_in[0];
    const float* k  = (const float*)d_in[1];
    const float* v  = (const float*)d_in[2];
    const float* Wq = (const float*)d_in[3];
    const float* Wk = (const float*)d_in[4];
    const float* Wv = (const float*)d_in[5];
    const float* Wo = (const float*)d_in[6];
    float* out = (float*)d_out;

    const size_t NW = (size_t)DMODEL * DMODEL;

    char* p = (char*)d_ws;
    f16* WqT = (f16*)p; p += NW * 2;
    f16* WkT = (f16*)p; p += NW * 2;
    f16* WvT = (f16*)p; p += NW * 2;
    f16* WoT = (f16*)p; p += NW * 2;
    f16* Qh  = (f16*)p; p += NQ_ELEMS * 2;
    f16* Kh  = (f16*)p; p += NKV_ELEMS * 2;
    f16* Vh  = (f16*)p; p += NKV_ELEMS * 2;
    float* attnw = (float*)p; p += (size_t)B_ * LKV_ * NH * SPAN * 4;
    f16* ctxh = (f16*)p; p += NQ_ELEMS * 2;

    // 1) weight transposes only (q/k/v convert folded into gemm_qkv)
    transpose_all<<<dim3(1024), 256, 0, stream>>>(Wq, Wk, Wv, Wo,
                                                  WqT, WkT, WvT, WoT);

    // 2) Q/K/V projections, pipelined 256x256, B via global_load_lds
    gemm_qkv<<<dim3(256), 512, 0, stream>>>(q, k, v, WqT, WkT, WvT, Qh, Kh, Vh);

    // 3) per-column masked scores + query-axis softmax
    attn_scores<<<dim3(LKV_ / 4, B_), 256, 0, stream>>>(Qh, Kh, attnw);

    // 4) per-query gather of weighted V
    ctx_gather<<<dim3(LQ_ / 16, B_), 256, 0, stream>>>(attnw, Vh, ctxh);

    // 5) output projection, full-DMA triple-buffered 256x128
    gemm_out<<<dim3(256), 512, 0, stream>>>(ctxh, WoT, out);
}

// Round 6
// 212.665 us; speedup vs baseline: 1.0827x; 1.0827x over previous
//
#include <hip/hip_runtime.h>
#include <cstdint>
#include <cstddef>

// ---------------------------------------------------------------------------
// SparseMHADecoder: B=2, LQ=4096, LKV=2048, D=1024, H=16, d=64, span=16, stride=2
// R12: revert GEMMs to the harness-verified R6 m97-structure (128x128 tile,
//      2-barrier loop, BOTH operands via global_load_lds w/ pre-swizzled src)
//      and hoist the f32->f16 input conversion into a streaming prep pass
//      (fused into the transpose kernel's grid). Rationale: R7-R11 showed all
//      schedule surgery lands at 62-89us with MfmaUtil 15-21%; the structural
//      delta vs m97's 37% MfmaUtil is the fused A-convert in the K-loop.
//      Pure-f16 staging removes 8 f32 loads + cvt + ds_writes + lgkm drain
//      per thread per K-tile from the GEMM critical path.
//      Workspace re-aliased: converted inputs die after gemm_qkv, so
//      ctxh aliases qf16 and attnw aliases kf16 (total 72 MB < previous 74).
// R10 carried: XCD A-panel grouping (R6 mapping), coalesced staging.
// R5/R6 carried: XOR chunk swizzle (0 bank conflicts in ALL rounds),
//      f16 numerics (absmax 0.015625 every round).
// ---------------------------------------------------------------------------

typedef _Float16 f16;
typedef _Float16 f16x8 __attribute__((ext_vector_type(8)));
typedef float v4f __attribute__((ext_vector_type(4)));

#define B_  2
#define LQ_ 4096
#define LKV_ 2048
#define DMODEL 1024
#define NH 16
#define HD 64
#define SPAN 16
#define STRIDE 2

#define NQ_ELEMS  ((size_t)B_ * LQ_ * DMODEL)   // 8388608
#define NKV_ELEMS ((size_t)B_ * LKV_ * DMODEL)  // 4194304

__device__ __forceinline__ void async_copy16(const f16* g, f16* l) {
    __builtin_amdgcn_global_load_lds((const __attribute__((address_space(1))) void*)g,
                                     (__attribute__((address_space(3))) void*)l, 16, 0, 0);
}

// ---- prep: 4 weight transposes (blocks 0..1023) + q/k/v f32->f16 convert ----
// Convert blocks: 2048 elems each; q: 4096 blocks, k: 2048, v: 2048.
__global__ __launch_bounds__(256)
void prep_all(const float* __restrict__ W0, const float* __restrict__ W1,
              const float* __restrict__ W2, const float* __restrict__ W3,
              f16* __restrict__ T0, f16* __restrict__ T1,
              f16* __restrict__ T2, f16* __restrict__ T3,
              const float* __restrict__ q, const float* __restrict__ k,
              const float* __restrict__ v,
              f16* __restrict__ qh, f16* __restrict__ kh, f16* __restrict__ vh) {
    const int t = threadIdx.x;
    const int bid = blockIdx.x;
    if (bid < 1024) {                       // 16x16 tiles x 4 weights
        const int z = bid >> 8, rem = bid & 255;
        const int bx = rem & 15, byy = rem >> 4;
        const float* W;
        f16* Wt;
        switch (z) {
            case 0: W = W0; Wt = T0; break;
            case 1: W = W1; Wt = T1; break;
            case 2: W = W2; Wt = T2; break;
            default: W = W3; Wt = T3; break;
        }
        __shared__ float tile[64][65];
        const int r0 = byy * 64, c0 = bx * 64;
        const int tx = t & 63, ty = t >> 6; // (64,4)
        for (int i = ty; i < 64; i += 4)
            tile[i][tx] = W[(long)(r0 + i) * DMODEL + c0 + tx];
        __syncthreads();
        for (int i = ty; i < 64; i += 4)
            Wt[(long)(c0 + i) * DMODEL + r0 + tx] = (f16)tile[tx][i];
    } else {                                // streaming f32 -> f16 convert
        const int cid = bid - 1024;         // 0..8191
        const float* src;
        f16* dst;
        size_t base;
        if (cid < 4096)      { src = q; dst = qh; base = (size_t)cid * 2048; }
        else if (cid < 6144) { src = k; dst = kh; base = (size_t)(cid - 4096) * 2048; }
        else                 { src = v; dst = vh; base = (size_t)(cid - 6144) * 2048; }
        const size_t i = base + (size_t)t * 8;
        const float4 lo = *(const float4*)(src + i);
        const float4 hi = *(const float4*)(src + i + 4);
        f16x8 o = {(f16)lo.x, (f16)lo.y, (f16)lo.z, (f16)lo.w,
                   (f16)hi.x, (f16)hi.y, (f16)hi.z, (f16)hi.w};
        *(f16x8*)(dst + i) = o;
    }
}

// ---------------- fp16 GEMM body, C[m][n] = sum_k A[m][k]*Bt[n][k] -----------
// 128x128 tile, BK=64, 256 thr = 4 waves, XOR chunk swizzle, BOTH operands
// via global_load_lds (pre-swizzled global src, linear LDS dest).
// This is the harness-verified R6 body with the A_F32 path removed —
// the m97 2-barrier structure (874-912 TF class on this chip).
template <bool OUT_F32>
__device__ __forceinline__ void gemm_body(const f16* __restrict__ Ah,
                                          const f16* __restrict__ Bt,
                                          void* __restrict__ Cv,
                                          int rowTile, int colTile) {
    constexpr int K = DMODEL, N = DMODEL;
    __shared__ f16 As[128 * 64];
    __shared__ f16 Bs[128 * 64];
    const int t = threadIdx.x;
    const int lane = t & 63;
    const int w = t >> 6;
    const int wm = w >> 1, wn = w & 1;
    const long rowBase = (long)rowTile * 128;
    const long colBase = (long)colTile * 128;
    const int qrow = lane & 15;
    const int quad = lane >> 4;

    v4f acc[4][4] = {};

    // staging: thread t covers rows srow+32i (i=0..3); LDS chunk schunk holds
    // global chunk schunk^(srow&7)  (8 f16 / 16B granularity)
    const int srow = t >> 3;          // 0..31
    const int schunk = t & 7;
    const int gchunk = schunk ^ (srow & 7);
    const f16* aptr = Ah + (rowBase + srow) * (long)K + gchunk * 8;
    const f16* bptr = Bt + (colBase + srow) * (long)K + gchunk * 8;
    f16* lA = &As[srow * 64 + schunk * 8];   // = t*8 : linear in t (DMA-legal)
    f16* lB = &Bs[srow * 64 + schunk * 8];

    for (int k0 = 0; k0 < K; k0 += 64) {
#pragma unroll
        for (int i = 0; i < 4; ++i)
            async_copy16(bptr + k0 + i * 32 * (long)K, lB + i * 2048);
#pragma unroll
        for (int i = 0; i < 4; ++i)
            async_copy16(aptr + k0 + i * 32 * (long)K, lA + i * 2048);
        __syncthreads();  // drains vmcnt+lgkm: staged tile visible
#pragma unroll
        for (int s = 0; s < 2; ++s) {   // two K=32 MFMA steps per BK=64 tile
            const int xk = (s * 4 + quad) ^ (qrow & 7);  // swizzled chunk
            f16x8 af[4], bf[4];
#pragma unroll
            for (int mt = 0; mt < 4; ++mt)
                af[mt] = *(const f16x8*)(&As[(wm * 64 + mt * 16 + qrow) * 64 + xk * 8]);
#pragma unroll
            for (int nt = 0; nt < 4; ++nt)
                bf[nt] = *(const f16x8*)(&Bs[(wn * 64 + nt * 16 + qrow) * 64 + xk * 8]);
#pragma unroll
            for (int mt = 0; mt < 4; ++mt)
#pragma unroll
                for (int nt = 0; nt < 4; ++nt)
                    acc[mt][nt] = __builtin_amdgcn_mfma_f32_16x16x32_f16(
                        af[mt], bf[nt], acc[mt][nt], 0, 0, 0);
        }
        __syncthreads();  // all reads done before next stage overwrites
    }

    // C/D layout (m89-verified): row = quad*4 + r, col = lane&15
#pragma unroll
    for (int mt = 0; mt < 4; ++mt)
#pragma unroll
        for (int nt = 0; nt < 4; ++nt) {
            const long col = colBase + wn * 64 + nt * 16 + qrow;
#pragma unroll
            for (int r = 0; r < 4; ++r) {
                const long row = rowBase + wm * 64 + mt * 16 + quad * 4 + r;
                if (OUT_F32)
                    ((float*)Cv)[row * (long)N + col] = acc[mt][nt][r];
                else
                    ((f16*)Cv)[row * (long)N + col] = (f16)acc[mt][nt][r];
            }
        }
}

// Fused Q/K/V projection from CONVERTED f16 inputs, 1024 blocks,
// XCD-swizzled (R4/R6-verified mapping: FETCH -82% vs naive).
__global__ __launch_bounds__(256, 2)
void gemm_qkv(const f16* __restrict__ A0, const f16* __restrict__ A1,
              const f16* __restrict__ A2, const f16* __restrict__ B0,
              const f16* __restrict__ B1, const f16* __restrict__ B2,
              f16* __restrict__ C0, f16* __restrict__ C1, f16* __restrict__ C2) {
    const int id = blockIdx.x;
    const int xcd = id & 7;
    const int g = id >> 3;            // 0..127
    const int ct = g & 7;             // col tile
    int rowIdx = (g >> 3) + xcd * 16; // 0..127
    const f16* A;
    const f16* Bt;
    f16* C;
    if (rowIdx < 64) {
        A = A0; Bt = B0; C = C0;
    } else if (rowIdx < 96) {
        A = A1; Bt = B1; C = C1; rowIdx -= 64;
    } else {
        A = A2; Bt = B2; C = C2; rowIdx -= 96;
    }
    gemm_body<false>(A, Bt, (void*)C, rowIdx, ct);
}

__global__ __launch_bounds__(256, 2)
void gemm_out(const f16* __restrict__ A, const f16* __restrict__ Bt,
              float* __restrict__ C) {
    const int id = blockIdx.x;        // 512 blocks
    const int xcd = id & 7;
    const int g = id >> 3;            // 0..63
    const int ct = g & 7;
    const int rowIdx = (g >> 3) + xcd * 8;  // 0..63
    gemm_body<true>(A, Bt, (void*)C, rowIdx, ct);
}

// -------- per-column scores + softmax over the 16 valid query rows ----------
__global__ __launch_bounds__(256)
void attn_scores(const f16* __restrict__ Q, const f16* __restrict__ Km,
                 float* __restrict__ attnw) {
    const int c0 = blockIdx.x * 4, b = blockIdx.y;
    const int t = threadIdx.x;
    __shared__ f16 Qs[24 * 1032];   // rows 0..21 used; 49.5 KB
    __shared__ f16 Ks[4 * 1032];    // 8.25 KB

#pragma unroll
    for (int it = 0; it < 12; ++it) {
        const int ch = t + 256 * it;        // 24 rows x 128 chunks
        const int row = ch >> 7, off = (ch & 127) * 8;
        int qq = 2 * c0 + row;
        if (qq > LQ_ - 1) qq = LQ_ - 1;     // clamp staging; masked in score
        f16x8 x = *(const f16x8*)(Q + (size_t)(b * LQ_ + qq) * DMODEL + off);
        const int h = off >> 6, bb = (off >> 3) & 7;
        *(f16x8*)(&Qs[row * 1032 + h * 64 + ((bb + h) & 7) * 8]) = x;
    }
#pragma unroll
    for (int it = 0; it < 2; ++it) {
        const int ch = t + 256 * it;        // 4 rows x 128 chunks
        const int row = ch >> 7, off = (ch & 127) * 8;
        f16x8 x = *(const f16x8*)(Km + (size_t)(b * LKV_ + c0 + row) * DMODEL + off);
        const int h = off >> 6, bb = (off >> 3) & 7;
        *(f16x8*)(&Ks[row * 1032 + h * 64 + ((bb + h) & 7) * 8]) = x;
    }
    __syncthreads();

    const int h = t >> 4, j = t & 15;
#pragma unroll
    for (int ci = 0; ci < 4; ++ci) {
        const int c = c0 + ci;
        const int q = STRIDE * c + j;
        const int row = 2 * ci + j;
        float a = 0.f;
#pragma unroll
        for (int bb = 0; bb < 8; ++bb) {
            const int off = h * 64 + ((bb + h) & 7) * 8;
            f16x8 qv = *(const f16x8*)(&Qs[row * 1032 + off]);
            f16x8 kv = *(const f16x8*)(&Ks[ci * 1032 + off]);  // wave-broadcast
#pragma unroll
            for (int u = 0; u < 8; ++u) a += (float)qv[u] * (float)kv[u];
        }
        float s = (q < LQ_) ? a : -1e30f;
        float m = s;
#pragma unroll
        for (int o = 1; o < 16; o <<= 1) m = fmaxf(m, __shfl_xor(m, o, 64));
        float p = (q < LQ_) ? __expf(s - m) : 0.f;
        float sum = p;
#pragma unroll
        for (int o = 1; o < 16; o <<= 1) sum += __shfl_xor(sum, o, 64);
        attnw[(size_t)((b * LKV_ + c) * NH + h) * SPAN + j] = p / sum;
    }
}

// ---- ctx[b,q,h,:] = sum_i attn[b, q/2-i, h, (q&1)+2i] * V[b, q/2-i, h, :] ----
__global__ __launch_bounds__(256)
void ctx_gather(const float* __restrict__ attnw, const f16* __restrict__ V,
                f16* __restrict__ ctx) {
    const int q0 = blockIdx.x * 16, b = blockIdx.y;
    const int t = threadIdx.x;
    const int kbase = (q0 >> 1) - 7;
    __shared__ f16 Vs[16 * 1024];     // 32 KB
    __shared__ float A_lds[16 * 256]; // 16 KB

#pragma unroll
    for (int it = 0; it < 8; ++it) {
        const int ch = t + 256 * it;       // 16 rows x 128 chunks
        const int row = ch >> 7, off = (ch & 127) * 8;
        int k = kbase + row;
        k = (k < 0) ? 0 : ((k > LKV_ - 1) ? LKV_ - 1 : k);
        *(f16x8*)(&Vs[row * 1024 + off]) =
            *(const f16x8*)(V + (size_t)(b * LKV_ + k) * DMODEL + off);
    }
#pragma unroll
    for (int it = 0; it < 4; ++it) {
        const int ch = t + 256 * it;       // 16 rows x 64 chunks of 4 f32
        const int row = ch >> 6, off = (ch & 63) * 4;
        int k = kbase + row;
        k = (k < 0) ? 0 : ((k > LKV_ - 1) ? LKV_ - 1 : k);
        *(float4*)(&A_lds[row * 256 + off]) =
            *(const float4*)(attnw + (size_t)(b * LKV_ + k) * 256 + off);
    }
    __syncthreads();

    const int d = t & 63;
    const int hg = t >> 6;
#pragma unroll
    for (int ql = 0; ql < 16; ++ql) {
        const int q = q0 + ql;
        const int j0 = q & 1;
        float acc[4] = {0.f, 0.f, 0.f, 0.f};
#pragma unroll
        for (int i = 0; i < SPAN / STRIDE; ++i) {
            const int kq = (q >> 1) - i;
            if (kq < 0) break;
            const int rr = kq - kbase;
#pragma unroll
            for (int hh = 0; hh < 4; ++hh) {
                const int h = hg * 4 + hh;
                acc[hh] += A_lds[rr * 256 + h * 16 + j0 + 2 * i] *
                           (float)Vs[rr * 1024 + h * 64 + d];
            }
        }
        f16* crow = ctx + (size_t)(b * LQ_ + q) * DMODEL;
#pragma unroll
        for (int hh = 0; hh < 4; ++hh) {
            const int h = hg * 4 + hh;
            crow[h * HD + d] = (f16)acc[hh];
        }
    }
}

// ---------------------------------------------------------------------------
extern "C" void kernel_launch(void* const* d_in, const int* in_sizes, int n_in,
                              void* d_out, int out_size, void* d_ws, size_t ws_size,
                              hipStream_t stream) {
    const float* q  = (const float*)d_in[0];
    const float* k  = (const float*)d_in[1];
    const float* v  = (const float*)d_in[2];
    const float* Wq = (const float*)d_in[3];
    const float* Wk = (const float*)d_in[4];
    const float* Wv = (const float*)d_in[5];
    const float* Wo = (const float*)d_in[6];
    float* out = (float*)d_out;

    const size_t NW = (size_t)DMODEL * DMODEL;

    char* p = (char*)d_ws;
    f16* WqT = (f16*)p; p += NW * 2;                    // 2 MB
    f16* WkT = (f16*)p; p += NW * 2;
    f16* WvT = (f16*)p; p += NW * 2;
    f16* WoT = (f16*)p; p += NW * 2;
    f16* Qh  = (f16*)p; p += NQ_ELEMS * 2;              // 16 MB
    f16* Kh  = (f16*)p; p += NKV_ELEMS * 2;             // 8 MB
    f16* Vh  = (f16*)p; p += NKV_ELEMS * 2;             // 8 MB
    f16* qf  = (f16*)p; p += NQ_ELEMS * 2;              // 16 MB (dead after qkv)
    f16* kf  = (f16*)p; p += NKV_ELEMS * 2;             // 8 MB  (dead after qkv)
    f16* vf  = (f16*)p; p += NKV_ELEMS * 2;             // 8 MB  (dead after qkv)
    // aliases (lifetimes verified: qf/kf dead once gemm_qkv completes)
    f16* ctxh = qf;                                     // 16 MB needed
    float* attnw = (float*)kf;                          // 4 MB needed <= 8 MB

    // 1) weight transposes + q/k/v f32->f16 convert (one fused launch)
    prep_all<<<dim3(9216), 256, 0, stream>>>(Wq, Wk, Wv, Wo, WqT, WkT, WvT, WoT,
                                             q, k, v, qf, kf, vf);

    // 2) Q/K/V projections, pure-f16 m97 structure, XCD-swizzled
    gemm_qkv<<<dim3(1024), 256, 0, stream>>>(qf, kf, vf, WqT, WkT, WvT,
                                             Qh, Kh, Vh);

    // 3) per-column masked scores + query-axis softmax
    attn_scores<<<dim3(LKV_ / 4, B_), 256, 0, stream>>>(Qh, Kh, attnw);

    // 4) per-query gather of weighted V
    ctx_gather<<<dim3(LQ_ / 16, B_), 256, 0, stream>>>(attnw, Vh, ctxh);

    // 5) output projection (f32 out), XCD-swizzled
    gemm_out<<<dim3(512), 256, 0, stream>>>(ctxh, WoT, out);
}